// Round 11
// baseline (220.710 us; speedup 1.0000x reference)
//
#include <hip/hip_runtime.h>

#define B_ 2
#define N_ 4096
#define M_ 2048
#define D_ 256
#define H_ 8
#define DH_ 32
#define ROWS_ (B_*N_)
#define KVROWS_ (B_*M_)
// SCALE * log2(e): q pre-scaled so softmax = exp2
#define PRE_ (0.17677669529663687f * 1.4426950408889634f)
#define CBASE_ 32.0f

typedef __attribute__((ext_vector_type(8))) short short8_t;
typedef __attribute__((ext_vector_type(4))) float float4_t;

#if defined(__has_builtin)
# if __has_builtin(__builtin_amdgcn_exp2f)
#  define EXP2F(x) __builtin_amdgcn_exp2f(x)
# else
#  define EXP2F(x) exp2f(x)
# endif
#else
# define EXP2F(x) exp2f(x)
#endif

// RTNE round-to-bf16 helper: rounded 32-bit word (bf16 in high half)
__device__ __forceinline__ unsigned int rne_u(float f) {
    union { float f; unsigned int u; } c;
    c.f = f;
    return c.u + 0x7FFFu + ((c.u >> 16) & 1u);
}

__device__ __forceinline__ unsigned short f2us(float f) {
    return (unsigned short)(rne_u(f) >> 16);
}

// pack two RTNE bf16: low16 = a, high16 = b  (single v_perm_b32 combine)
__device__ __forceinline__ unsigned int pack2rn(float a, float b) {
    return __builtin_amdgcn_perm(rne_u(b), rne_u(a), 0x07060302u);
}

// truncation pack (P tiles only; <=2^-8 rel err) — single v_perm_b32
__device__ __forceinline__ unsigned int pack2tr(float a, float b) {
    union { float f; unsigned int u; } x, y;
    x.f = a; y.f = b;
    return __builtin_amdgcn_perm(y.u, x.u, 0x07060302u);
}

__device__ __forceinline__ short8_t cvt8(float4 a, float4 b) {
    union { unsigned int u[4]; short8_t s; } c;
    c.u[0] = pack2rn(a.x, a.y);
    c.u[1] = pack2rn(a.z, a.w);
    c.u[2] = pack2rn(b.x, b.y);
    c.u[3] = pack2rn(b.z, b.w);
    return c.s;
}

// bijective XCD-aware block-id swizzle (valid when nwg % 8 == 0)
__device__ __forceinline__ int xcd_swz(int bid, int nwg) {
    const int cpx = nwg >> 3;
    return (bid & 7) * cpx + (bid >> 3);
}

// ---------------------------------------------------------------------------
// Stage NCOL x K fp32 weight block (source row stride LDSRC, col offset kof)
// into XOR-swizzled bf16 LDS.
// ---------------------------------------------------------------------------
template<int K, int NCOL, int LDSRC>
__device__ __forceinline__ void stageB2(const float* __restrict__ W, int col0, int kof,
                                        unsigned short* __restrict__ Bs, int tid)
{
    const int n = tid & (NCOL - 1), g = tid / NCOL;
    const int GROUPS = 256 / NCOL;
    const int CPT = (K / 8) / GROUPS;
    const float* src = W + (size_t)(col0 + n) * LDSRC + kof + g * (K / GROUPS);
#pragma unroll
    for (int ci = 0; ci < CPT; ci++) {
        int logc = g * CPT + ci;
        int phys = logc ^ (n & 7);
        short8_t v = cvt8(*(const float4*)(src + ci * 8), *(const float4*)(src + ci * 8 + 4));
        *(short8_t*)(Bs + (size_t)n * K + phys * 8) = v;
    }
}

template<int K>
__device__ __forceinline__ short8_t readB(const unsigned short* __restrict__ Bs,
                                          int c, int l16, int quad, int k0)
{
    int phys = ((k0 >> 3) + quad) ^ (l16 & 7);
    return *(const short8_t*)(Bs + (size_t)(16 * c + l16) * K + phys * 8);
}

// ---------------------------------------------------------------------------
// KV projection + weight-fold prep (r8 shape, verbatim).
// ---------------------------------------------------------------------------
__global__ __launch_bounds__(256) void g_projkv4(
    const float* __restrict__ voxel,
    const float* __restrict__ Wp, const float* __restrict__ bp,
    const float* __restrict__ Wq, const float* __restrict__ bq,
    const float* __restrict__ Wk, const float* __restrict__ bk,
    const float* __restrict__ Wv, const float* __restrict__ bv,
    const float* __restrict__ Wf, const float* __restrict__ bfb,
    unsigned short* __restrict__ k_g, unsigned short* __restrict__ vt_g,
    float* __restrict__ Wqc, float* __restrict__ Wfc)
{
    const int tid = threadIdx.x;
    const int wave = tid >> 6, lane = tid & 63, quad = lane >> 4, l16 = lane & 15;

    __shared__ unsigned short Bs[64 * 256];   // 32 KB

    const int bid = (int)blockIdx.x;
    if (bid < 512) {
        const int lbid = xcd_swz(bid, 512);
        const int row0 = (lbid >> 3) * 64;
        const int sub  = lbid & 7;
        const int col0 = (sub >> 1) * 64;
        const bool isV = sub & 1;

        stageB2<256, 64, 256>(isV ? Wv : Wk, col0, 0, Bs, tid);

        const float* arow = voxel + (size_t)(row0 + wave * 16 + l16) * D_;
        short8_t af[8];
#pragma unroll
        for (int i = 0; i < 8; i++)
            af[i] = cvt8(*(const float4*)(arow + i * 32 + quad * 8),
                         *(const float4*)(arow + i * 32 + quad * 8 + 4));

        float4_t acc[4];
#pragma unroll
        for (int c = 0; c < 4; c++) acc[c] = (float4_t){0.f, 0.f, 0.f, 0.f};
        __syncthreads();
#pragma unroll
        for (int i = 0; i < 8; i++)
#pragma unroll
            for (int c = 0; c < 4; c++)
                acc[c] = __builtin_amdgcn_mfma_f32_16x16x32_bf16(af[i], readB<256>(Bs, c, l16, quad, i * 32), acc[c], 0, 0, 0);

        if (!isV) {
#pragma unroll
            for (int c = 0; c < 4; c++) {
                int col = col0 + 16 * c + l16;
                float bbk = bk[col];
#pragma unroll
                for (int r = 0; r < 4; r++) {
                    int row = row0 + wave * 16 + quad * 4 + r;
                    k_g[(size_t)row * D_ + col] = f2us(acc[c][r] + bbk);
                }
            }
        } else {
            const int b = row0 / M_;
            const int m0 = row0 - b * M_ + wave * 16 + quad * 4;
#pragma unroll
            for (int c = 0; c < 4; c++) {
                int col = col0 + 16 * c + l16;
                float bbv = bv[col];
                int h = col >> 5, dh = col & 31;
                unsigned int u0 = pack2rn(acc[c][0] + bbv, acc[c][1] + bbv);
                unsigned int u1 = pack2rn(acc[c][2] + bbv, acc[c][3] + bbv);
                *(uint2*)(vt_g + (size_t)((b * H_ + h) * DH_ + dh) * M_ + m0) = make_uint2(u0, u1);
            }
        }
    } else {
        // ---- prep role: fold fan-in-3 weights in f32 (exact) ----
        const int role = bid - 512;               // 0: Wqc, 1: Wfc
        float* wps = (float*)Bs;                  // [256][4] staged Wp|bp
        *(float4*)(wps + tid * 4) = make_float4(Wp[tid * 3 + 0], Wp[tid * 3 + 1],
                                                Wp[tid * 3 + 2], bp[tid]);
        __syncthreads();
        const int col = tid;
        const float* wrow = role ? (Wf + (size_t)col * 512) : (Wq + (size_t)col * 256);
        float a0 = 0.f, a1 = 0.f, a2 = 0.f, ab = 0.f;
#pragma unroll 4
        for (int d = 0; d < 256; d += 4) {
            float4 wv = *(const float4*)(wrow + d);
            float4 w0 = *(const float4*)(wps + (d + 0) * 4);
            float4 w1 = *(const float4*)(wps + (d + 1) * 4);
            float4 w2 = *(const float4*)(wps + (d + 2) * 4);
            float4 w3 = *(const float4*)(wps + (d + 3) * 4);
            a0 += wv.x * w0.x + wv.y * w1.x + wv.z * w2.x + wv.w * w3.x;
            a1 += wv.x * w0.y + wv.y * w1.y + wv.z * w2.y + wv.w * w3.y;
            a2 += wv.x * w0.z + wv.y * w1.z + wv.z * w2.z + wv.w * w3.z;
            ab += wv.x * w0.w + wv.y * w1.w + wv.z * w2.w + wv.w * w3.w;
        }
        if (role == 0) {
            *(float4*)(Wqc + (size_t)col * 4) =
                make_float4(a0 * PRE_, a1 * PRE_, a2 * PRE_, (ab + bq[col]) * PRE_);
        } else {
            *(float4*)(Wfc + (size_t)col * 4) =
                make_float4(a0, a1, a2, ab + bfb[col]);
        }
    }
}

// ---------------------------------------------------------------------------
// MFMA flash attention v14: NO LDS, NO BARRIERS (m169 pattern: K/V per head
// = 256 KB, L2-resident — staging it through LDS was pure overhead).
// Each wave independent, 16 q-rows. K fragments read directly from k_g with
// the g_t row permutation (P lands in PV B-fragment order, as r5-r8);
// V fragments read directly from vt_g. Register A/B prefetch (static
// indexing) hides L2 latency under the previous step's exp2+MFMA.
// Grid 1024 x 256 thr -> 16 waves/CU; launch_bounds(256,4) caps VGPR at 128.
// Math/rounding bit-identical to r8 -> absmax unchanged.
// ---------------------------------------------------------------------------
__global__ __launch_bounds__(256, 4) void k_attn14(
    const float* __restrict__ points, const float* __restrict__ Wqc,
    const unsigned short* __restrict__ k_g,
    const unsigned short* __restrict__ vt_g,
    unsigned short* __restrict__ att_g)
{
    const int tid = threadIdx.x;
    const int w = tid >> 6, lane = tid & 63, quad = lane >> 4, l16 = lane & 15;
    const int lbid = xcd_swz((int)blockIdx.x, B_ * H_ * (N_ / 64));
    const int nt = lbid & 63;             // N/64
    const int bh = lbid >> 6;             // b*8+h
    const int b = bh >> 3, h = bh & 7;
    const int n0 = nt * 64 + w * 16;

    const unsigned short* kbase = k_g + (size_t)(b * M_) * D_ + h * DH_;
    const unsigned short* vbase = vt_g + (size_t)bh * DH_ * M_;

    // per-lane K row base (g_t permutation, applied directly to global rows)
    const int g0 = 8 * (l16 >> 2) + (l16 & 3);
    const unsigned short* kp0 = kbase + (size_t)g0 * D_ + quad * 8;   // rows g0, g0+4
    const unsigned short* kp2 = kp0 + 32 * D_;                        // rows g0+32, g0+36
    const unsigned short* vp0 = vbase + (size_t)l16 * M_ + quad * 8;  // dh = l16
    const unsigned short* vp1 = vp0 + (size_t)16 * M_;                // dh = 16+l16

    // q inline: row = b*N_ + n0 + l16, cols h*32 + quad*8 + j  (f32-exact)
    const size_t qrow = (size_t)(b * N_ + n0 + l16);
    const float p0 = points[qrow * 3 + 0];
    const float p1 = points[qrow * 3 + 1];
    const float p2 = points[qrow * 3 + 2];
    float q8[8];
#pragma unroll
    for (int j = 0; j < 8; j++) {
        float4 wc = *(const float4*)(Wqc + (size_t)(h * DH_ + quad * 8 + j) * 4);
        q8[j] = p0 * wc.x + p1 * wc.y + p2 * wc.z + wc.w;
    }
    short8_t qf = cvt8(make_float4(q8[0], q8[1], q8[2], q8[3]),
                       make_float4(q8[4], q8[5], q8[6], q8[7]));

    // all-ones bf16 A-fragment for the l-sum MFMA
    short8_t ones;
#pragma unroll
    for (int j = 0; j < 8; j++) ones[j] = (short)0x3F80;

    float4_t od0 = {0.f, 0.f, 0.f, 0.f};
    float4_t od1 = {0.f, 0.f, 0.f, 0.f};
    float4_t lacc = {0.f, 0.f, 0.f, 0.f};
    const float4_t zc = {-CBASE_, -CBASE_, -CBASE_, -CBASE_};

    short8_t kA[4], vA[4], kB[4], vB[4];

#define LOADS(KR, VR, S_)                                                    \
    do {                                                                     \
        const size_t ko = (size_t)(S_) * (64 * D_);                          \
        const size_t vo = (size_t)(S_) * 64;                                 \
        KR[0] = *(const short8_t*)(kp0 + ko);                                \
        KR[1] = *(const short8_t*)(kp0 + ko + 4 * D_);                       \
        KR[2] = *(const short8_t*)(kp2 + ko);                                \
        KR[3] = *(const short8_t*)(kp2 + ko + 4 * D_);                       \
        VR[0] = *(const short8_t*)(vp0 + vo);                                \
        VR[1] = *(const short8_t*)(vp0 + vo + 32);                           \
        VR[2] = *(const short8_t*)(vp1 + vo);                                \
        VR[3] = *(const short8_t*)(vp1 + vo + 32);                           \
    } while (0)

#define COMPUTE(KR, VR)                                                         \
    do {                                                                        \
        float4_t st[4];                                                         \
        _Pragma("unroll")                                                       \
        for (int t = 0; t < 4; t++)                                             \
            st[t] = __builtin_amdgcn_mfma_f32_16x16x32_bf16(KR[t], qf, zc, 0, 0, 0); \
        unsigned int uu[4][2];                                                  \
        _Pragma("unroll")                                                       \
        for (int t = 0; t < 4; t++) {                                           \
            float e0 = EXP2F(st[t][0]);                                         \
            float e1 = EXP2F(st[t][1]);                                         \
            float e2 = EXP2F(st[t][2]);                                         \
            float e3 = EXP2F(st[t][3]);                                         \
            uu[t][0] = pack2tr(e0, e1);                                         \
            uu[t][1] = pack2tr(e2, e3);                                         \
        }                                                                       \
        union { unsigned int u[4]; short8_t s; } pa, pb2;                       \
        pa.u[0]  = uu[0][0]; pa.u[1]  = uu[0][1];                               \
        pa.u[2]  = uu[1][0]; pa.u[3]  = uu[1][1];                               \
        pb2.u[0] = uu[2][0]; pb2.u[1] = uu[2][1];                               \
        pb2.u[2] = uu[3][0]; pb2.u[3] = uu[3][1];                               \
        lacc = __builtin_amdgcn_mfma_f32_16x16x32_bf16(ones, pa.s,  lacc, 0, 0, 0); \
        lacc = __builtin_amdgcn_mfma_f32_16x16x32_bf16(ones, pb2.s, lacc, 0, 0, 0); \
        od0 = __builtin_amdgcn_mfma_f32_16x16x32_bf16(VR[0], pa.s,  od0, 0, 0, 0); \
        od0 = __builtin_amdgcn_mfma_f32_16x16x32_bf16(VR[1], pb2.s, od0, 0, 0, 0); \
        od1 = __builtin_amdgcn_mfma_f32_16x16x32_bf16(VR[2], pa.s,  od1, 0, 0, 0); \
        od1 = __builtin_amdgcn_mfma_f32_16x16x32_bf16(VR[3], pb2.s, od1, 0, 0, 0); \
    } while (0)

    LOADS(kA, vA, 0);
    for (int s = 0; s < M_ / 64; s += 2) {
        LOADS(kB, vB, s + 1);
        COMPUTE(kA, vA);
        if (s + 2 < M_ / 64) LOADS(kA, vA, s + 2);
        COMPUTE(kB, vB);
    }
#undef LOADS
#undef COMPUTE

    const float inv = 1.0f / lacc[0];

    unsigned short* ob = att_g + (size_t)(b * N_ + n0 + l16) * D_ + h * DH_;
    {
        unsigned int u0 = pack2rn(od0[0] * inv, od0[1] * inv);
        unsigned int u1 = pack2rn(od0[2] * inv, od0[3] * inv);
        *(uint2*)(ob + quad * 4) = make_uint2(u0, u1);
        unsigned int u2 = pack2rn(od1[0] * inv, od1[1] * inv);
        unsigned int u3 = pack2rn(od1[2] * inv, od1[3] * inv);
        *(uint2*)(ob + 16 + quad * 4) = make_uint2(u2, u3);
    }
}

// ---------------------------------------------------------------------------
// Fuse: out = att@Wf2.T + points@Wfc.T (bias folded), fp32 out.
// 64x64 tiles (512 blocks), r8 shape verbatim.
// ---------------------------------------------------------------------------
__global__ __launch_bounds__(256) void g_fuse3(
    const unsigned short* __restrict__ att_g,
    const float* __restrict__ points, const float* __restrict__ Wfc,
    const float* __restrict__ Wf,
    float* __restrict__ out)
{
    const int tid = threadIdx.x;
    const int wave = tid >> 6, lane = tid & 63, quad = lane >> 4, l16 = lane & 15;
    const int lbid = xcd_swz((int)blockIdx.x, (ROWS_ / 64) * 4);
    const int row0 = (lbid >> 2) * 64;
    const int col0 = (lbid & 3) * 64;

    __shared__ unsigned short Bs[64 * 256];  // 32 KB (Wf cols 256..511)

    stageB2<256, 64, 512>(Wf, col0, 256, Bs, tid);
    __syncthreads();

    float4_t acc[4];
#pragma unroll
    for (int c = 0; c < 4; c++) acc[c] = (float4_t){0.f, 0.f, 0.f, 0.f};

    const size_t arow = (size_t)(row0 + wave * 16 + l16) * D_;
#pragma unroll
    for (int k0 = 0; k0 < 256; k0 += 32) {
        short8_t af = *(const short8_t*)(att_g + arow + k0 + quad * 8);
#pragma unroll
        for (int c = 0; c < 4; c++)
            acc[c] = __builtin_amdgcn_mfma_f32_16x16x32_bf16(af, readB<256>(Bs, c, l16, quad, k0), acc[c], 0, 0, 0);
    }

    const int rbase = row0 + wave * 16 + quad * 4;
    float px[4], py[4], pz[4];
#pragma unroll
    for (int r = 0; r < 4; r++) {
        px[r] = points[(size_t)(rbase + r) * 3 + 0];
        py[r] = points[(size_t)(rbase + r) * 3 + 1];
        pz[r] = points[(size_t)(rbase + r) * 3 + 2];
    }
#pragma unroll
    for (int c = 0; c < 4; c++) {
        int col = col0 + 16 * c + l16;
        float4 wf = *(const float4*)(Wfc + (size_t)col * 4);
#pragma unroll
        for (int r = 0; r < 4; r++) {
            out[(size_t)(rbase + r) * D_ + col] =
                acc[c][r] + px[r] * wf.x + py[r] * wf.y + pz[r] * wf.z + wf.w;
        }
    }
}

// ---------------------------------------------------------------------------
extern "C" void kernel_launch(void* const* d_in, const int* in_sizes, int n_in,
                              void* d_out, int out_size, void* d_ws, size_t ws_size,
                              hipStream_t stream)
{
    const float* points = (const float*)d_in[0];
    const float* voxel  = (const float*)d_in[1];
    const float* Wp  = (const float*)d_in[2];
    const float* bp  = (const float*)d_in[3];
    const float* Wq  = (const float*)d_in[4];
    const float* bq  = (const float*)d_in[5];
    const float* Wk  = (const float*)d_in[6];
    const float* bk  = (const float*)d_in[7];
    const float* Wv  = (const float*)d_in[8];
    const float* bv  = (const float*)d_in[9];
    const float* Wf  = (const float*)d_in[10];
    const float* bfb = (const float*)d_in[11];
    float* out = (float*)d_out;

    float* Wqc = (float*)d_ws;                         // [256][4] f32
    float* Wfc = Wqc + 256 * 4;                        // [256][4] f32
    unsigned short* k_g   = (unsigned short*)(Wfc + 256 * 4);
    unsigned short* vt_g  = k_g  + (size_t)KVROWS_ * D_;   // [b][h][dh][m]
    unsigned short* att_g = vt_g + (size_t)KVROWS_ * D_;

    g_projkv4<<<dim3(514), dim3(256), 0, stream>>>(voxel, Wp, bp, Wq, bq, Wk, bk,
                                                   Wv, bv, Wf, bfb, k_g, vt_g, Wqc, Wfc);
    k_attn14<<<dim3(B_ * H_ * (N_ / 64)), dim3(256), 0, stream>>>(points, Wqc, k_g, vt_g, att_g);
    g_fuse3 <<<dim3((ROWS_ / 64) * 4), dim3(256), 0, stream>>>(att_g, points, Wfc, Wf, out);
}

// Round 12
// 132.421 us; speedup vs baseline: 1.6667x; 1.6667x over previous
//
#include <hip/hip_runtime.h>

#define B_ 2
#define N_ 4096
#define M_ 2048
#define D_ 256
#define H_ 8
#define DH_ 32
#define ROWS_ (B_*N_)
#define KVROWS_ (B_*M_)
// SCALE * log2(e): q pre-scaled so softmax = exp2
#define PRE_ (0.17677669529663687f * 1.4426950408889634f)
#define CBASE_ 32.0f

typedef __attribute__((ext_vector_type(8))) short short8_t;
typedef __attribute__((ext_vector_type(4))) float float4_t;

#if defined(__has_builtin)
# if __has_builtin(__builtin_amdgcn_exp2f)
#  define EXP2F(x) __builtin_amdgcn_exp2f(x)
# else
#  define EXP2F(x) exp2f(x)
# endif
#else
# define EXP2F(x) exp2f(x)
#endif

// RTNE round-to-bf16 helper: rounded 32-bit word (bf16 in high half)
__device__ __forceinline__ unsigned int rne_u(float f) {
    union { float f; unsigned int u; } c;
    c.f = f;
    return c.u + 0x7FFFu + ((c.u >> 16) & 1u);
}

__device__ __forceinline__ unsigned short f2us(float f) {
    return (unsigned short)(rne_u(f) >> 16);
}

// pack two RTNE bf16: low16 = a, high16 = b  (single v_perm_b32 combine)
__device__ __forceinline__ unsigned int pack2rn(float a, float b) {
    return __builtin_amdgcn_perm(rne_u(b), rne_u(a), 0x07060302u);
}

// truncation pack (P tiles only; <=2^-8 rel err) — single v_perm_b32
__device__ __forceinline__ unsigned int pack2tr(float a, float b) {
    union { float f; unsigned int u; } x, y;
    x.f = a; y.f = b;
    return __builtin_amdgcn_perm(y.u, x.u, 0x07060302u);
}

__device__ __forceinline__ short8_t cvt8(float4 a, float4 b) {
    union { unsigned int u[4]; short8_t s; } c;
    c.u[0] = pack2rn(a.x, a.y);
    c.u[1] = pack2rn(a.z, a.w);
    c.u[2] = pack2rn(b.x, b.y);
    c.u[3] = pack2rn(b.z, b.w);
    return c.s;
}

// bijective XCD-aware block-id swizzle (valid when nwg % 8 == 0)
__device__ __forceinline__ int xcd_swz(int bid, int nwg) {
    const int cpx = nwg >> 3;
    return (bid & 7) * cpx + (bid >> 3);
}

// ---------------------------------------------------------------------------
// Stage NCOL x K fp32 weight block (source row stride LDSRC, col offset kof)
// into XOR-swizzled bf16 LDS.
// ---------------------------------------------------------------------------
template<int K, int NCOL, int LDSRC>
__device__ __forceinline__ void stageB2(const float* __restrict__ W, int col0, int kof,
                                        unsigned short* __restrict__ Bs, int tid)
{
    const int n = tid & (NCOL - 1), g = tid / NCOL;
    const int GROUPS = 256 / NCOL;
    const int CPT = (K / 8) / GROUPS;
    const float* src = W + (size_t)(col0 + n) * LDSRC + kof + g * (K / GROUPS);
#pragma unroll
    for (int ci = 0; ci < CPT; ci++) {
        int logc = g * CPT + ci;
        int phys = logc ^ (n & 7);
        short8_t v = cvt8(*(const float4*)(src + ci * 8), *(const float4*)(src + ci * 8 + 4));
        *(short8_t*)(Bs + (size_t)n * K + phys * 8) = v;
    }
}

template<int K>
__device__ __forceinline__ short8_t readB(const unsigned short* __restrict__ Bs,
                                          int c, int l16, int quad, int k0)
{
    int phys = ((k0 >> 3) + quad) ^ (l16 & 7);
    return *(const short8_t*)(Bs + (size_t)(16 * c + l16) * K + phys * 8);
}

// ---------------------------------------------------------------------------
// KV projection + weight-fold prep (r8 shape, verbatim).
// ---------------------------------------------------------------------------
__global__ __launch_bounds__(256) void g_projkv4(
    const float* __restrict__ voxel,
    const float* __restrict__ Wp, const float* __restrict__ bp,
    const float* __restrict__ Wq, const float* __restrict__ bq,
    const float* __restrict__ Wk, const float* __restrict__ bk,
    const float* __restrict__ Wv, const float* __restrict__ bv,
    const float* __restrict__ Wf, const float* __restrict__ bfb,
    unsigned short* __restrict__ k_g, unsigned short* __restrict__ vt_g,
    float* __restrict__ Wqc, float* __restrict__ Wfc)
{
    const int tid = threadIdx.x;
    const int wave = tid >> 6, lane = tid & 63, quad = lane >> 4, l16 = lane & 15;

    __shared__ unsigned short Bs[64 * 256];   // 32 KB

    const int bid = (int)blockIdx.x;
    if (bid < 512) {
        const int lbid = xcd_swz(bid, 512);
        const int row0 = (lbid >> 3) * 64;
        const int sub  = lbid & 7;
        const int col0 = (sub >> 1) * 64;
        const bool isV = sub & 1;

        stageB2<256, 64, 256>(isV ? Wv : Wk, col0, 0, Bs, tid);

        const float* arow = voxel + (size_t)(row0 + wave * 16 + l16) * D_;
        short8_t af[8];
#pragma unroll
        for (int i = 0; i < 8; i++)
            af[i] = cvt8(*(const float4*)(arow + i * 32 + quad * 8),
                         *(const float4*)(arow + i * 32 + quad * 8 + 4));

        float4_t acc[4];
#pragma unroll
        for (int c = 0; c < 4; c++) acc[c] = (float4_t){0.f, 0.f, 0.f, 0.f};
        __syncthreads();
#pragma unroll
        for (int i = 0; i < 8; i++)
#pragma unroll
            for (int c = 0; c < 4; c++)
                acc[c] = __builtin_amdgcn_mfma_f32_16x16x32_bf16(af[i], readB<256>(Bs, c, l16, quad, i * 32), acc[c], 0, 0, 0);

        if (!isV) {
#pragma unroll
            for (int c = 0; c < 4; c++) {
                int col = col0 + 16 * c + l16;
                float bbk = bk[col];
#pragma unroll
                for (int r = 0; r < 4; r++) {
                    int row = row0 + wave * 16 + quad * 4 + r;
                    k_g[(size_t)row * D_ + col] = f2us(acc[c][r] + bbk);
                }
            }
        } else {
            const int b = row0 / M_;
            const int m0 = row0 - b * M_ + wave * 16 + quad * 4;
#pragma unroll
            for (int c = 0; c < 4; c++) {
                int col = col0 + 16 * c + l16;
                float bbv = bv[col];
                int h = col >> 5, dh = col & 31;
                unsigned int u0 = pack2rn(acc[c][0] + bbv, acc[c][1] + bbv);
                unsigned int u1 = pack2rn(acc[c][2] + bbv, acc[c][3] + bbv);
                *(uint2*)(vt_g + (size_t)((b * H_ + h) * DH_ + dh) * M_ + m0) = make_uint2(u0, u1);
            }
        }
    } else {
        // ---- prep role: fold fan-in-3 weights in f32 (exact) ----
        const int role = bid - 512;               // 0: Wqc, 1: Wfc
        float* wps = (float*)Bs;                  // [256][4] staged Wp|bp
        *(float4*)(wps + tid * 4) = make_float4(Wp[tid * 3 + 0], Wp[tid * 3 + 1],
                                                Wp[tid * 3 + 2], bp[tid]);
        __syncthreads();
        const int col = tid;
        const float* wrow = role ? (Wf + (size_t)col * 512) : (Wq + (size_t)col * 256);
        float a0 = 0.f, a1 = 0.f, a2 = 0.f, ab = 0.f;
#pragma unroll 4
        for (int d = 0; d < 256; d += 4) {
            float4 wv = *(const float4*)(wrow + d);
            float4 w0 = *(const float4*)(wps + (d + 0) * 4);
            float4 w1 = *(const float4*)(wps + (d + 1) * 4);
            float4 w2 = *(const float4*)(wps + (d + 2) * 4);
            float4 w3 = *(const float4*)(wps + (d + 3) * 4);
            a0 += wv.x * w0.x + wv.y * w1.x + wv.z * w2.x + wv.w * w3.x;
            a1 += wv.x * w0.y + wv.y * w1.y + wv.z * w2.y + wv.w * w3.y;
            a2 += wv.x * w0.z + wv.y * w1.z + wv.z * w2.z + wv.w * w3.z;
            ab += wv.x * w0.w + wv.y * w1.w + wv.z * w2.w + wv.w * w3.w;
        }
        if (role == 0) {
            *(float4*)(Wqc + (size_t)col * 4) =
                make_float4(a0 * PRE_, a1 * PRE_, a2 * PRE_, (ab + bq[col]) * PRE_);
        } else {
            *(float4*)(Wfc + (size_t)col * 4) =
                make_float4(a0, a1, a2, ab + bfb[col]);
        }
    }
}

// ---------------------------------------------------------------------------
// MFMA flash attention v11 (r8 verbatim): 128 q-rows/block, 512 threads.
//  - permuted-K QK^T -> P directly in PV B-fragment order
//  - 4-buffer LDS pipeline, ONE barrier per 2 steps
//  - l-sum on the MFMA pipe (mfma(ones, P) row-sum)
// LDS: Kt[4][64][40] 20 KB + Vt[4][32][72] 18 KB = 38 KB -> 2 blocks/CU.
// ---------------------------------------------------------------------------
__global__ __launch_bounds__(512) void k_attn11(
    const float* __restrict__ points, const float* __restrict__ Wqc,
    const unsigned short* __restrict__ k_g,
    const unsigned short* __restrict__ vt_g,
    unsigned short* __restrict__ att_g)
{
    const int tid = threadIdx.x;
    const int w = tid >> 6, lane = tid & 63, quad = lane >> 4, l16 = lane & 15;
    const int lbid = xcd_swz((int)blockIdx.x, B_ * H_ * (N_ / 128));
    const int nt = lbid & 31;             // N/128
    const int bh = lbid >> 5;             // b*8+h
    const int b = bh >> 3, h = bh & 7;
    const int n0 = nt * 128 + w * 16;

    __shared__ unsigned short Kt[4][64][40];   // 20 KB
    __shared__ unsigned short Vt[4][32][72];   // 18 KB

    const unsigned short* kbase = k_g + (size_t)(b * M_) * D_ + h * DH_;
    const unsigned short* vbase = vt_g + (size_t)(bh * DH_) * M_;

    // staging role: one 16B chunk per thread per step
    const bool isK = (tid < 256);
    const int kr = tid >> 2, kc = tid & 3;            // K: 64 rows x 4 chunks
    const int vr = (tid - 256) >> 3, vc = tid & 7;    // V: 32 rows x 8 chunks
    const int ksr = kr ^ ((kr & 8) >> 1);             // rho-permuted K LDS row

    const int gstep = isK ? 64 * D_ : 64;
    const unsigned short* gq = isK ? (kbase + (size_t)kr * D_ + kc * 8)
                                   : (vbase + (size_t)vr * M_ + vc * 8);
    unsigned short* ldst = isK ? (&Kt[0][0][0] + ksr * 40 + kc * 8)
                               : (&Vt[0][0][0] + vr * 72 + vc * 8);
    const int lstride = isK ? 2560 : 2304;            // buf stride in shorts

    // prologue: stage steps 0,1 into bufs 0,1
    *(short8_t*)ldst = *(const short8_t*)gq;
    gq += gstep;
    *(short8_t*)(ldst + lstride) = *(const short8_t*)gq;

    // permuted K-row read indices (rho applied; XOR safe: bit2 never carries)
    const int rbas = 8 * (l16 >> 2) + (l16 & 3);
    const int rx = l16 & 4;
    int krow[4];
#pragma unroll
    for (int t = 0; t < 4; t++)
        krow[t] = (rbas + 4 * (t & 1) + 32 * (t >> 1)) ^ rx;

    // q inline: row = b*N_ + n0 + l16, cols h*32 + quad*8 + j  (f32-exact)
    const size_t qrow = (size_t)(b * N_ + n0 + l16);
    const float p0 = points[qrow * 3 + 0];
    const float p1 = points[qrow * 3 + 1];
    const float p2 = points[qrow * 3 + 2];
    float q8[8];
#pragma unroll
    for (int j = 0; j < 8; j++) {
        float4 wc = *(const float4*)(Wqc + (size_t)(h * DH_ + quad * 8 + j) * 4);
        q8[j] = p0 * wc.x + p1 * wc.y + p2 * wc.z + wc.w;
    }
    short8_t qf = cvt8(make_float4(q8[0], q8[1], q8[2], q8[3]),
                       make_float4(q8[4], q8[5], q8[6], q8[7]));

    // all-ones bf16 A-fragment for the l-sum MFMA
    short8_t ones;
#pragma unroll
    for (int j = 0; j < 8; j++) ones[j] = (short)0x3F80;

    float4_t od0 = {0.f, 0.f, 0.f, 0.f};
    float4_t od1 = {0.f, 0.f, 0.f, 0.f};
    float4_t lacc = {0.f, 0.f, 0.f, 0.f};

    const float4_t zc = {-CBASE_, -CBASE_, -CBASE_, -CBASE_};

    __syncthreads();

#define STEPC(KB_, VB_)                                                         \
    do {                                                                        \
        float4_t st[4];                                                         \
        _Pragma("unroll")                                                       \
        for (int t = 0; t < 4; t++) {                                           \
            short8_t kf = *(const short8_t*)&Kt[KB_][krow[t]][quad * 8];        \
            st[t] = __builtin_amdgcn_mfma_f32_16x16x32_bf16(kf, qf, zc, 0, 0, 0); \
        }                                                                       \
        unsigned int uu[4][2];                                                  \
        _Pragma("unroll")                                                       \
        for (int t = 0; t < 4; t++) {                                           \
            float e0 = EXP2F(st[t][0]);                                         \
            float e1 = EXP2F(st[t][1]);                                         \
            float e2 = EXP2F(st[t][2]);                                         \
            float e3 = EXP2F(st[t][3]);                                         \
            uu[t][0] = pack2tr(e0, e1);                                         \
            uu[t][1] = pack2tr(e2, e3);                                         \
        }                                                                       \
        union { unsigned int u[4]; short8_t s; } pa, pb2;                       \
        pa.u[0]  = uu[0][0]; pa.u[1]  = uu[0][1];                               \
        pa.u[2]  = uu[1][0]; pa.u[3]  = uu[1][1];                               \
        pb2.u[0] = uu[2][0]; pb2.u[1] = uu[2][1];                               \
        pb2.u[2] = uu[3][0]; pb2.u[3] = uu[3][1];                               \
        lacc = __builtin_amdgcn_mfma_f32_16x16x32_bf16(ones, pa.s,  lacc, 0, 0, 0); \
        lacc = __builtin_amdgcn_mfma_f32_16x16x32_bf16(ones, pb2.s, lacc, 0, 0, 0); \
        short8_t vf00 = *(const short8_t*)&Vt[VB_][l16][quad * 8];              \
        short8_t vf01 = *(const short8_t*)&Vt[VB_][l16][32 + quad * 8];         \
        short8_t vf10 = *(const short8_t*)&Vt[VB_][16 + l16][quad * 8];         \
        short8_t vf11 = *(const short8_t*)&Vt[VB_][16 + l16][32 + quad * 8];    \
        od0 = __builtin_amdgcn_mfma_f32_16x16x32_bf16(vf00, pa.s,  od0, 0, 0, 0); \
        od0 = __builtin_amdgcn_mfma_f32_16x16x32_bf16(vf01, pb2.s, od0, 0, 0, 0); \
        od1 = __builtin_amdgcn_mfma_f32_16x16x32_bf16(vf10, pa.s,  od1, 0, 0, 0); \
        od1 = __builtin_amdgcn_mfma_f32_16x16x32_bf16(vf11, pb2.s, od1, 0, 0, 0); \
    } while (0)

#pragma unroll 2
    for (int s = 0; s < M_ / 64; s += 2) {
        const bool m0 = (s + 2 < M_ / 64);
        const bool m1 = (s + 3 < M_ / 64);
        short8_t nxt0, nxt1;
        if (m0) { gq += gstep; nxt0 = *(const short8_t*)gq; }
        if (m1) { gq += gstep; nxt1 = *(const short8_t*)gq; }

        STEPC((s) & 3, (s) & 3);
        STEPC((s + 1) & 3, (s + 1) & 3);

        if (m0) *(short8_t*)(ldst + ((s + 2) & 3) * lstride) = nxt0;
        if (m1) *(short8_t*)(ldst + ((s + 3) & 3) * lstride) = nxt1;
        __syncthreads();
    }
#undef STEPC

    const float inv = 1.0f / lacc[0];

    unsigned short* ob = att_g + (size_t)(b * N_ + n0 + l16) * D_ + h * DH_;
    {
        unsigned int u0 = pack2rn(od0[0] * inv, od0[1] * inv);
        unsigned int u1 = pack2rn(od0[2] * inv, od0[3] * inv);
        *(uint2*)(ob + quad * 4) = make_uint2(u0, u1);
        unsigned int u2 = pack2rn(od1[0] * inv, od1[1] * inv);
        unsigned int u3 = pack2rn(od1[2] * inv, od1[3] * inv);
        *(uint2*)(ob + 16 + quad * 4) = make_uint2(u2, u3);
    }
}

// ---------------------------------------------------------------------------
// Fuse: out = att@Wf2.T + points@Wfc.T (bias folded), fp32 out.
// 64x64 tiles (512 blocks), r8 shape verbatim.
// ---------------------------------------------------------------------------
__global__ __launch_bounds__(256) void g_fuse3(
    const unsigned short* __restrict__ att_g,
    const float* __restrict__ points, const float* __restrict__ Wfc,
    const float* __restrict__ Wf,
    float* __restrict__ out)
{
    const int tid = threadIdx.x;
    const int wave = tid >> 6, lane = tid & 63, quad = lane >> 4, l16 = lane & 15;
    const int lbid = xcd_swz((int)blockIdx.x, (ROWS_ / 64) * 4);
    const int row0 = (lbid >> 2) * 64;
    const int col0 = (lbid & 3) * 64;

    __shared__ unsigned short Bs[64 * 256];  // 32 KB (Wf cols 256..511)

    stageB2<256, 64, 512>(Wf, col0, 256, Bs, tid);
    __syncthreads();

    float4_t acc[4];
#pragma unroll
    for (int c = 0; c < 4; c++) acc[c] = (float4_t){0.f, 0.f, 0.f, 0.f};

    const size_t arow = (size_t)(row0 + wave * 16 + l16) * D_;
#pragma unroll
    for (int k0 = 0; k0 < 256; k0 += 32) {
        short8_t af = *(const short8_t*)(att_g + arow + k0 + quad * 8);
#pragma unroll
        for (int c = 0; c < 4; c++)
            acc[c] = __builtin_amdgcn_mfma_f32_16x16x32_bf16(af, readB<256>(Bs, c, l16, quad, k0), acc[c], 0, 0, 0);
    }

    const int rbase = row0 + wave * 16 + quad * 4;
    float px[4], py[4], pz[4];
#pragma unroll
    for (int r = 0; r < 4; r++) {
        px[r] = points[(size_t)(rbase + r) * 3 + 0];
        py[r] = points[(size_t)(rbase + r) * 3 + 1];
        pz[r] = points[(size_t)(rbase + r) * 3 + 2];
    }
#pragma unroll
    for (int c = 0; c < 4; c++) {
        int col = col0 + 16 * c + l16;
        float4 wf = *(const float4*)(Wfc + (size_t)col * 4);
#pragma unroll
        for (int r = 0; r < 4; r++) {
            out[(size_t)(rbase + r) * D_ + col] =
                acc[c][r] + px[r] * wf.x + py[r] * wf.y + pz[r] * wf.z + wf.w;
        }
    }
}

// ---------------------------------------------------------------------------
extern "C" void kernel_launch(void* const* d_in, const int* in_sizes, int n_in,
                              void* d_out, int out_size, void* d_ws, size_t ws_size,
                              hipStream_t stream)
{
    const float* points = (const float*)d_in[0];
    const float* voxel  = (const float*)d_in[1];
    const float* Wp  = (const float*)d_in[2];
    const float* bp  = (const float*)d_in[3];
    const float* Wq  = (const float*)d_in[4];
    const float* bq  = (const float*)d_in[5];
    const float* Wk  = (const float*)d_in[6];
    const float* bk  = (const float*)d_in[7];
    const float* Wv  = (const float*)d_in[8];
    const float* bv  = (const float*)d_in[9];
    const float* Wf  = (const float*)d_in[10];
    const float* bfb = (const float*)d_in[11];
    float* out = (float*)d_out;

    float* Wqc = (float*)d_ws;                         // [256][4] f32
    float* Wfc = Wqc + 256 * 4;                        // [256][4] f32
    unsigned short* k_g   = (unsigned short*)(Wfc + 256 * 4);
    unsigned short* vt_g  = k_g  + (size_t)KVROWS_ * D_;   // [b][h][dh][m]
    unsigned short* att_g = vt_g + (size_t)KVROWS_ * D_;

    g_projkv4<<<dim3(514), dim3(256), 0, stream>>>(voxel, Wp, bp, Wq, bq, Wk, bk,
                                                   Wv, bv, Wf, bfb, k_g, vt_g, Wqc, Wfc);
    k_attn11<<<dim3(B_ * H_ * (N_ / 128)), dim3(512), 0, stream>>>(points, Wqc, k_g, vt_g, att_g);
    g_fuse3 <<<dim3((ROWS_ / 64) * 4), dim3(256), 0, stream>>>(att_g, points, Wfc, Wf, out);
}

// Round 13
// 131.927 us; speedup vs baseline: 1.6730x; 1.0037x over previous
//
#include <hip/hip_runtime.h>

#define B_ 2
#define N_ 4096
#define M_ 2048
#define D_ 256
#define H_ 8
#define DH_ 32
#define ROWS_ (B_*N_)
#define KVROWS_ (B_*M_)
// SCALE * log2(e): q pre-scaled so softmax = exp2
#define PRE_ (0.17677669529663687f * 1.4426950408889634f)
#define CBASE_ 32.0f

typedef __attribute__((ext_vector_type(8))) short short8_t;
typedef __attribute__((ext_vector_type(4))) float float4_t;

#if defined(__has_builtin)
# if __has_builtin(__builtin_amdgcn_exp2f)
#  define EXP2F(x) __builtin_amdgcn_exp2f(x)
# else
#  define EXP2F(x) exp2f(x)
# endif
#else
# define EXP2F(x) exp2f(x)
#endif

// RTNE round-to-bf16 helper: rounded 32-bit word (bf16 in high half)
__device__ __forceinline__ unsigned int rne_u(float f) {
    union { float f; unsigned int u; } c;
    c.f = f;
    return c.u + 0x7FFFu + ((c.u >> 16) & 1u);
}

__device__ __forceinline__ unsigned short f2us(float f) {
    return (unsigned short)(rne_u(f) >> 16);
}

// pack two RTNE bf16: low16 = a, high16 = b  (single v_perm_b32 combine)
__device__ __forceinline__ unsigned int pack2rn(float a, float b) {
    return __builtin_amdgcn_perm(rne_u(b), rne_u(a), 0x07060302u);
}

// truncation pack (P tiles only; <=2^-8 rel err) — single v_perm_b32
__device__ __forceinline__ unsigned int pack2tr(float a, float b) {
    union { float f; unsigned int u; } x, y;
    x.f = a; y.f = b;
    return __builtin_amdgcn_perm(y.u, x.u, 0x07060302u);
}

__device__ __forceinline__ short8_t cvt8(float4 a, float4 b) {
    union { unsigned int u[4]; short8_t s; } c;
    c.u[0] = pack2rn(a.x, a.y);
    c.u[1] = pack2rn(a.z, a.w);
    c.u[2] = pack2rn(b.x, b.y);
    c.u[3] = pack2rn(b.z, b.w);
    return c.s;
}

// bijective XCD-aware block-id swizzle (valid when nwg % 8 == 0)
__device__ __forceinline__ int xcd_swz(int bid, int nwg) {
    const int cpx = nwg >> 3;
    return (bid & 7) * cpx + (bid >> 3);
}

// ---------------------------------------------------------------------------
// Stage NCOL x K fp32 weight block (source row stride LDSRC, col offset kof)
// into XOR-swizzled bf16 LDS.
// ---------------------------------------------------------------------------
template<int K, int NCOL, int LDSRC>
__device__ __forceinline__ void stageB2(const float* __restrict__ W, int col0, int kof,
                                        unsigned short* __restrict__ Bs, int tid)
{
    const int n = tid & (NCOL - 1), g = tid / NCOL;
    const int GROUPS = 256 / NCOL;
    const int CPT = (K / 8) / GROUPS;
    const float* src = W + (size_t)(col0 + n) * LDSRC + kof + g * (K / GROUPS);
#pragma unroll
    for (int ci = 0; ci < CPT; ci++) {
        int logc = g * CPT + ci;
        int phys = logc ^ (n & 7);
        short8_t v = cvt8(*(const float4*)(src + ci * 8), *(const float4*)(src + ci * 8 + 4));
        *(short8_t*)(Bs + (size_t)n * K + phys * 8) = v;
    }
}

template<int K>
__device__ __forceinline__ short8_t readB(const unsigned short* __restrict__ Bs,
                                          int c, int l16, int quad, int k0)
{
    int phys = ((k0 >> 3) + quad) ^ (l16 & 7);
    return *(const short8_t*)(Bs + (size_t)(16 * c + l16) * K + phys * 8);
}

// ---------------------------------------------------------------------------
// KV projection + weight-fold prep.
// blocks [0,512): tile 64 rows x 64 cols, K or V (32KB LDS -> 2 blocks/CU);
//   lbid layout (row,col,kv) grouped under xcd_swz for voxel L2 locality.
// block 512: Wqc[256][4] = PRE_*(Wq@Wp | Wq@bp+bq)   (q folded to fan-in 3)
// block 513: Wfc[256][4] = (Wf1@Wp | Wf1@bp+bf)      (pf-half of fuse folded)
// ---------------------------------------------------------------------------
__global__ __launch_bounds__(256) void g_projkv4(
    const float* __restrict__ voxel,
    const float* __restrict__ Wp, const float* __restrict__ bp,
    const float* __restrict__ Wq, const float* __restrict__ bq,
    const float* __restrict__ Wk, const float* __restrict__ bk,
    const float* __restrict__ Wv, const float* __restrict__ bv,
    const float* __restrict__ Wf, const float* __restrict__ bfb,
    unsigned short* __restrict__ k_g, unsigned short* __restrict__ vt_g,
    float* __restrict__ Wqc, float* __restrict__ Wfc)
{
    const int tid = threadIdx.x;
    const int wave = tid >> 6, lane = tid & 63, quad = lane >> 4, l16 = lane & 15;

    __shared__ unsigned short Bs[64 * 256];   // 32 KB

    const int bid = (int)blockIdx.x;
    if (bid < 512) {
        const int lbid = xcd_swz(bid, 512);
        const int row0 = (lbid >> 3) * 64;
        const int sub  = lbid & 7;
        const int col0 = (sub >> 1) * 64;
        const bool isV = sub & 1;

        stageB2<256, 64, 256>(isV ? Wv : Wk, col0, 0, Bs, tid);

        const float* arow = voxel + (size_t)(row0 + wave * 16 + l16) * D_;
        short8_t af[8];
#pragma unroll
        for (int i = 0; i < 8; i++)
            af[i] = cvt8(*(const float4*)(arow + i * 32 + quad * 8),
                         *(const float4*)(arow + i * 32 + quad * 8 + 4));

        float4_t acc[4];
#pragma unroll
        for (int c = 0; c < 4; c++) acc[c] = (float4_t){0.f, 0.f, 0.f, 0.f};
        __syncthreads();
#pragma unroll
        for (int i = 0; i < 8; i++)
#pragma unroll
            for (int c = 0; c < 4; c++)
                acc[c] = __builtin_amdgcn_mfma_f32_16x16x32_bf16(af[i], readB<256>(Bs, c, l16, quad, i * 32), acc[c], 0, 0, 0);

        if (!isV) {
#pragma unroll
            for (int c = 0; c < 4; c++) {
                int col = col0 + 16 * c + l16;
                float bbk = bk[col];
#pragma unroll
                for (int r = 0; r < 4; r++) {
                    int row = row0 + wave * 16 + quad * 4 + r;
                    k_g[(size_t)row * D_ + col] = f2us(acc[c][r] + bbk);
                }
            }
        } else {
            const int b = row0 / M_;
            const int m0 = row0 - b * M_ + wave * 16 + quad * 4;
#pragma unroll
            for (int c = 0; c < 4; c++) {
                int col = col0 + 16 * c + l16;
                float bbv = bv[col];
                int h = col >> 5, dh = col & 31;
                unsigned int u0 = pack2rn(acc[c][0] + bbv, acc[c][1] + bbv);
                unsigned int u1 = pack2rn(acc[c][2] + bbv, acc[c][3] + bbv);
                *(uint2*)(vt_g + (size_t)((b * H_ + h) * DH_ + dh) * M_ + m0) = make_uint2(u0, u1);
            }
        }
    } else {
        // ---- prep role: fold fan-in-3 weights in f32 (exact) ----
        const int role = bid - 512;               // 0: Wqc, 1: Wfc
        float* wps = (float*)Bs;                  // [256][4] staged Wp|bp
        *(float4*)(wps + tid * 4) = make_float4(Wp[tid * 3 + 0], Wp[tid * 3 + 1],
                                                Wp[tid * 3 + 2], bp[tid]);
        __syncthreads();
        const int col = tid;
        const float* wrow = role ? (Wf + (size_t)col * 512) : (Wq + (size_t)col * 256);
        float a0 = 0.f, a1 = 0.f, a2 = 0.f, ab = 0.f;
#pragma unroll 4
        for (int d = 0; d < 256; d += 4) {
            float4 wv = *(const float4*)(wrow + d);
            float4 w0 = *(const float4*)(wps + (d + 0) * 4);
            float4 w1 = *(const float4*)(wps + (d + 1) * 4);
            float4 w2 = *(const float4*)(wps + (d + 2) * 4);
            float4 w3 = *(const float4*)(wps + (d + 3) * 4);
            a0 += wv.x * w0.x + wv.y * w1.x + wv.z * w2.x + wv.w * w3.x;
            a1 += wv.x * w0.y + wv.y * w1.y + wv.z * w2.y + wv.w * w3.y;
            a2 += wv.x * w0.z + wv.y * w1.z + wv.z * w2.z + wv.w * w3.z;
            ab += wv.x * w0.w + wv.y * w1.w + wv.z * w2.w + wv.w * w3.w;
        }
        if (role == 0) {
            *(float4*)(Wqc + (size_t)col * 4) =
                make_float4(a0 * PRE_, a1 * PRE_, a2 * PRE_, (ab + bq[col]) * PRE_);
        } else {
            *(float4*)(Wfc + (size_t)col * 4) =
                make_float4(a0, a1, a2, ab + bfb[col]);
        }
    }
}

// ---------------------------------------------------------------------------
// MFMA flash attention v11: 128 q-rows/block, 512 threads (8 waves).
//  - permuted-K QK^T -> P directly in PV B-fragment order (no P LDS trip)
//  - 4-buffer LDS pipeline, ONE barrier per 2 steps (16 barriers total)
//  - l-sum on the MFMA pipe (mfma(ones, P) row-sum; same bf16 P as PV)
// LDS: Kt[4][64][40] 20 KB + Vt[4][32][72] 18 KB = 38 KB -> 2 blocks/CU.
// ---------------------------------------------------------------------------
__global__ __launch_bounds__(512) void k_attn11(
    const float* __restrict__ points, const float* __restrict__ Wqc,
    const unsigned short* __restrict__ k_g,
    const unsigned short* __restrict__ vt_g,
    unsigned short* __restrict__ att_g)
{
    const int tid = threadIdx.x;
    const int w = tid >> 6, lane = tid & 63, quad = lane >> 4, l16 = lane & 15;
    const int lbid = xcd_swz((int)blockIdx.x, B_ * H_ * (N_ / 128));
    const int nt = lbid & 31;             // N/128
    const int bh = lbid >> 5;             // b*8+h
    const int b = bh >> 3, h = bh & 7;
    const int n0 = nt * 128 + w * 16;

    __shared__ unsigned short Kt[4][64][40];   // 20 KB
    __shared__ unsigned short Vt[4][32][72];   // 18 KB

    const unsigned short* kbase = k_g + (size_t)(b * M_) * D_ + h * DH_;
    const unsigned short* vbase = vt_g + (size_t)(bh * DH_) * M_;

    // staging role: one 16B chunk per thread per step
    const bool isK = (tid < 256);
    const int kr = tid >> 2, kc = tid & 3;            // K: 64 rows x 4 chunks
    const int vr = (tid - 256) >> 3, vc = tid & 7;    // V: 32 rows x 8 chunks
    const int ksr = kr ^ ((kr & 8) >> 1);             // rho-permuted K LDS row

    const int gstep = isK ? 64 * D_ : 64;
    const unsigned short* gq = isK ? (kbase + (size_t)kr * D_ + kc * 8)
                                   : (vbase + (size_t)vr * M_ + vc * 8);
    unsigned short* ldst = isK ? (&Kt[0][0][0] + ksr * 40 + kc * 8)
                               : (&Vt[0][0][0] + vr * 72 + vc * 8);
    const int lstride = isK ? 2560 : 2304;            // buf stride in shorts

    // prologue: stage steps 0,1 into bufs 0,1
    *(short8_t*)ldst = *(const short8_t*)gq;
    gq += gstep;
    *(short8_t*)(ldst + lstride) = *(const short8_t*)gq;

    // permuted K-row read indices (rho applied; XOR safe: bit2 never carries)
    const int rbas = 8 * (l16 >> 2) + (l16 & 3);
    const int rx = l16 & 4;
    int krow[4];
#pragma unroll
    for (int t = 0; t < 4; t++)
        krow[t] = (rbas + 4 * (t & 1) + 32 * (t >> 1)) ^ rx;

    // q inline: row = b*N_ + n0 + l16, cols h*32 + quad*8 + j  (f32-exact)
    const size_t qrow = (size_t)(b * N_ + n0 + l16);
    const float p0 = points[qrow * 3 + 0];
    const float p1 = points[qrow * 3 + 1];
    const float p2 = points[qrow * 3 + 2];
    float q8[8];
#pragma unroll
    for (int j = 0; j < 8; j++) {
        float4 wc = *(const float4*)(Wqc + (size_t)(h * DH_ + quad * 8 + j) * 4);
        q8[j] = p0 * wc.x + p1 * wc.y + p2 * wc.z + wc.w;
    }
    short8_t qf = cvt8(make_float4(q8[0], q8[1], q8[2], q8[3]),
                       make_float4(q8[4], q8[5], q8[6], q8[7]));

    // all-ones bf16 A-fragment for the l-sum MFMA
    short8_t ones;
#pragma unroll
    for (int j = 0; j < 8; j++) ones[j] = (short)0x3F80;

    float4_t od0 = {0.f, 0.f, 0.f, 0.f};
    float4_t od1 = {0.f, 0.f, 0.f, 0.f};
    float4_t lacc = {0.f, 0.f, 0.f, 0.f};

    const float4_t zc = {-CBASE_, -CBASE_, -CBASE_, -CBASE_};

    __syncthreads();

#define STEPC(KB_, VB_)                                                         \
    do {                                                                        \
        float4_t st[4];                                                         \
        _Pragma("unroll")                                                       \
        for (int t = 0; t < 4; t++) {                                           \
            short8_t kf = *(const short8_t*)&Kt[KB_][krow[t]][quad * 8];        \
            st[t] = __builtin_amdgcn_mfma_f32_16x16x32_bf16(kf, qf, zc, 0, 0, 0); \
        }                                                                       \
        unsigned int uu[4][2];                                                  \
        _Pragma("unroll")                                                       \
        for (int t = 0; t < 4; t++) {                                           \
            float e0 = EXP2F(st[t][0]);                                         \
            float e1 = EXP2F(st[t][1]);                                         \
            float e2 = EXP2F(st[t][2]);                                         \
            float e3 = EXP2F(st[t][3]);                                         \
            uu[t][0] = pack2tr(e0, e1);                                         \
            uu[t][1] = pack2tr(e2, e3);                                         \
        }                                                                       \
        union { unsigned int u[4]; short8_t s; } pa, pb2;                       \
        pa.u[0]  = uu[0][0]; pa.u[1]  = uu[0][1];                               \
        pa.u[2]  = uu[1][0]; pa.u[3]  = uu[1][1];                               \
        pb2.u[0] = uu[2][0]; pb2.u[1] = uu[2][1];                               \
        pb2.u[2] = uu[3][0]; pb2.u[3] = uu[3][1];                               \
        lacc = __builtin_amdgcn_mfma_f32_16x16x32_bf16(ones, pa.s,  lacc, 0, 0, 0); \
        lacc = __builtin_amdgcn_mfma_f32_16x16x32_bf16(ones, pb2.s, lacc, 0, 0, 0); \
        short8_t vf00 = *(const short8_t*)&Vt[VB_][l16][quad * 8];              \
        short8_t vf01 = *(const short8_t*)&Vt[VB_][l16][32 + quad * 8];         \
        short8_t vf10 = *(const short8_t*)&Vt[VB_][16 + l16][quad * 8];         \
        short8_t vf11 = *(const short8_t*)&Vt[VB_][16 + l16][32 + quad * 8];    \
        od0 = __builtin_amdgcn_mfma_f32_16x16x32_bf16(vf00, pa.s,  od0, 0, 0, 0); \
        od0 = __builtin_amdgcn_mfma_f32_16x16x32_bf16(vf01, pb2.s, od0, 0, 0, 0); \
        od1 = __builtin_amdgcn_mfma_f32_16x16x32_bf16(vf10, pa.s,  od1, 0, 0, 0); \
        od1 = __builtin_amdgcn_mfma_f32_16x16x32_bf16(vf11, pb2.s, od1, 0, 0, 0); \
    } while (0)

#pragma unroll 2
    for (int s = 0; s < M_ / 64; s += 2) {
        const bool m0 = (s + 2 < M_ / 64);
        const bool m1 = (s + 3 < M_ / 64);
        short8_t nxt0, nxt1;
        if (m0) { gq += gstep; nxt0 = *(const short8_t*)gq; }
        if (m1) { gq += gstep; nxt1 = *(const short8_t*)gq; }

        STEPC((s) & 3, (s) & 3);
        STEPC((s + 1) & 3, (s + 1) & 3);

        if (m0) *(short8_t*)(ldst + ((s + 2) & 3) * lstride) = nxt0;
        if (m1) *(short8_t*)(ldst + ((s + 3) & 3) * lstride) = nxt1;
        __syncthreads();
    }
#undef STEPC

    const float inv = 1.0f / lacc[0];

    unsigned short* ob = att_g + (size_t)(b * N_ + n0 + l16) * D_ + h * DH_;
    {
        unsigned int u0 = pack2rn(od0[0] * inv, od0[1] * inv);
        unsigned int u1 = pack2rn(od0[2] * inv, od0[3] * inv);
        *(uint2*)(ob + quad * 4) = make_uint2(u0, u1);
        unsigned int u2 = pack2rn(od1[0] * inv, od1[1] * inv);
        unsigned int u3 = pack2rn(od1[2] * inv, od1[3] * inv);
        *(uint2*)(ob + 16 + quad * 4) = make_uint2(u2, u3);
    }
}

// ---------------------------------------------------------------------------
// Fuse: out = att@Wf2.T + points@Wfc.T (bias folded), fp32 out.
// 64x64 tiles (512 blocks).
// ---------------------------------------------------------------------------
__global__ __launch_bounds__(256) void g_fuse3(
    const unsigned short* __restrict__ att_g,
    const float* __restrict__ points, const float* __restrict__ Wfc,
    const float* __restrict__ Wf,
    float* __restrict__ out)
{
    const int tid = threadIdx.x;
    const int wave = tid >> 6, lane = tid & 63, quad = lane >> 4, l16 = lane & 15;
    const int lbid = xcd_swz((int)blockIdx.x, (ROWS_ / 64) * 4);
    const int row0 = (lbid >> 2) * 64;
    const int col0 = (lbid & 3) * 64;

    __shared__ unsigned short Bs[64 * 256];  // 32 KB (Wf cols 256..511)

    stageB2<256, 64, 512>(Wf, col0, 256, Bs, tid);
    __syncthreads();

    float4_t acc[4];
#pragma unroll
    for (int c = 0; c < 4; c++) acc[c] = (float4_t){0.f, 0.f, 0.f, 0.f};

    const size_t arow = (size_t)(row0 + wave * 16 + l16) * D_;
#pragma unroll
    for (int k0 = 0; k0 < 256; k0 += 32) {
        short8_t af = *(const short8_t*)(att_g + arow + k0 + quad * 8);
#pragma unroll
        for (int c = 0; c < 4; c++)
            acc[c] = __builtin_amdgcn_mfma_f32_16x16x32_bf16(af, readB<256>(Bs, c, l16, quad, k0), acc[c], 0, 0, 0);
    }

    const int rbase = row0 + wave * 16 + quad * 4;
    float px[4], py[4], pz[4];
#pragma unroll
    for (int r = 0; r < 4; r++) {
        px[r] = points[(size_t)(rbase + r) * 3 + 0];
        py[r] = points[(size_t)(rbase + r) * 3 + 1];
        pz[r] = points[(size_t)(rbase + r) * 3 + 2];
    }
#pragma unroll
    for (int c = 0; c < 4; c++) {
        int col = col0 + 16 * c + l16;
        float4 wf = *(const float4*)(Wfc + (size_t)col * 4);
#pragma unroll
        for (int r = 0; r < 4; r++) {
            out[(size_t)(rbase + r) * D_ + col] =
                acc[c][r] + px[r] * wf.x + py[r] * wf.y + pz[r] * wf.z + wf.w;
        }
    }
}

// ---------------------------------------------------------------------------
extern "C" void kernel_launch(void* const* d_in, const int* in_sizes, int n_in,
                              void* d_out, int out_size, void* d_ws, size_t ws_size,
                              hipStream_t stream)
{
    const float* points = (const float*)d_in[0];
    const float* voxel  = (const float*)d_in[1];
    const float* Wp  = (const float*)d_in[2];
    const float* bp  = (const float*)d_in[3];
    const float* Wq  = (const float*)d_in[4];
    const float* bq  = (const float*)d_in[5];
    const float* Wk  = (const float*)d_in[6];
    const float* bk  = (const float*)d_in[7];
    const float* Wv  = (const float*)d_in[8];
    const float* bv  = (const float*)d_in[9];
    const float* Wf  = (const float*)d_in[10];
    const float* bfb = (const float*)d_in[11];
    float* out = (float*)d_out;

    float* Wqc = (float*)d_ws;                         // [256][4] f32
    float* Wfc = Wqc + 256 * 4;                        // [256][4] f32
    unsigned short* k_g   = (unsigned short*)(Wfc + 256 * 4);
    unsigned short* vt_g  = k_g  + (size_t)KVROWS_ * D_;   // [b][h][dh][m]
    unsigned short* att_g = vt_g + (size_t)KVROWS_ * D_;

    g_projkv4<<<dim3(514), dim3(256), 0, stream>>>(voxel, Wp, bp, Wq, bq, Wk, bk,
                                                   Wv, bv, Wf, bfb, k_g, vt_g, Wqc, Wfc);
    k_attn11<<<dim3(B_ * H_ * (N_ / 128)), dim3(512), 0, stream>>>(points, Wqc, k_g, vt_g, att_g);
    g_fuse3 <<<dim3((ROWS_ / 64) * 4), dim3(256), 0, stream>>>(att_g, points, Wfc, Wf, out);
}